// Round 5
// baseline (174.993 us; speedup 1.0000x reference)
//
#include <hip/hip_runtime.h>

// out[i,j] = eps[i]*eps_perm[i]*rho/(2*pi*sigma) * exp(-||nuc_i - sb_j||^2/(2*sigma))
//          + eps[i]*d_drop[i]*chi_ambient[j]
// N = 8192 rows (CBs), M = 4096 cols (SBs).
//
// LEARNED (rounds 0-4) — unique combo consistent with ALL observations:
//  - Inputs: float32, INSERTION (setup_inputs dict) order, as documented:
//      [0]=nuc_locations [1]=SB_locations [2]=epsilon_perm [3]=epsilon
//      [4]=d_drop [5]=rho_SB [6]=sigma_SB [7]=chi_ambient
//  - Output: FLOAT32 (not bf16 — the "(bf16,...)" test label is a hardcoded
//    template string). R2 had correct f32 reads + insertion mapping and failed
//    ONLY because it packed bf16 ushorts into the f32 output (half-buffer
//    written, err == max|ref| == 0.15625 signature). R1/R4 NaNs = bf16 read of
//    f32 sigma (low ushort of 1.0f = 0) -> sig=0 -> inf*0.
//
// Write-BW-bound: 134 MB f32 output. One block per row, 256 threads,
// float4 (16 B) per thread per store, 4 passes over M=4096.

__global__ __launch_bounds__(256) void rate_kernel(
    const float* __restrict__ nuc,          // [N,2]
    const float* __restrict__ sb,           // [M,2]
    const float* __restrict__ epsilon_perm, // [N]
    const float* __restrict__ epsilon,      // [N]
    const float* __restrict__ d_drop,       // [N]
    const float* __restrict__ rho_SB,       // [1]
    const float* __restrict__ sigma_SB,     // [1]
    const float* __restrict__ chi,          // [M]
    float* __restrict__ out,                // [N,M] f32
    int M)
{
    const int row = blockIdx.x;
    const int tid = threadIdx.x;

    // per-row scalars (block-uniform -> scalar loads)
    const float2 nxy = ((const float2*)nuc)[row];
    const float nx  = nxy.x;
    const float ny  = nxy.y;
    const float e   = epsilon[row];
    const float ep  = epsilon_perm[row];
    const float dd  = d_drop[row];
    const float rho = rho_SB[0];
    const float sig = sigma_SB[0];

    // exp(-d2/(2s)) = exp2(d2 * (-1/(2s)) * log2(e))
    const float scale = (-0.5f / sig) * 1.4426950408889634f;
    // exp(-log(2pi) - log(sigma)) = 1/(2*pi*sigma)
    const float coef = e * ep * rho * (0.15915494309189535f / sig);
    const float lamc = e * dd;

    float* orow = out + (size_t)row * (size_t)M;
    const float4* sb4  = (const float4*)sb;   // 2 (x,y) pairs per float4
    const float4* chi4 = (const float4*)chi;

    for (int j0 = tid * 4; j0 < M; j0 += 256 * 4) {
        // 4 SB pairs = 8 floats = 2x float4; 4 chi = 1x float4
        const float4 s0 = sb4[j0 / 2];
        const float4 s1 = sb4[j0 / 2 + 1];
        const float4 cv = chi4[j0 / 4];

        const float sx[4] = { s0.x, s0.z, s1.x, s1.z };
        const float sy[4] = { s0.y, s0.w, s1.y, s1.w };
        const float ch[4] = { cv.x, cv.y, cv.z, cv.w };

        float4 res;
        float* resp = (float*)&res;
#pragma unroll
        for (int k = 0; k < 4; ++k) {
            const float dx = nx - sx[k];
            const float dy = ny - sy[k];
            const float d2 = fmaf(dx, dx, dy * dy);
            const float ev = exp2f(d2 * scale);
            resp[k] = fmaf(coef, ev, lamc * ch[k]);
        }
        *(float4*)(orow + j0) = res;
    }
}

extern "C" void kernel_launch(void* const* d_in, const int* in_sizes, int n_in,
                              void* d_out, int out_size, void* d_ws, size_t ws_size,
                              hipStream_t stream) {
    // INSERTION (setup_inputs dict) order — see header comment.
    const float* nuc = (const float*)d_in[0]; // nuc_locations [N,2]
    const float* sb  = (const float*)d_in[1]; // SB_locations [M,2]
    const float* epp = (const float*)d_in[2]; // epsilon_perm [N]
    const float* eps = (const float*)d_in[3]; // epsilon [N]
    const float* ddp = (const float*)d_in[4]; // d_drop [N]
    const float* rho = (const float*)d_in[5]; // rho_SB [1]
    const float* sig = (const float*)d_in[6]; // sigma_SB [1]
    const float* chi = (const float*)d_in[7]; // chi_ambient [M]
    float* out = (float*)d_out;

    const int M = in_sizes[7];   // 4096 (chi_ambient)
    const int N = out_size / M;  // 8192

    rate_kernel<<<N, 256, 0, stream>>>(nuc, sb, epp, eps, ddp, rho, sig, chi, out, M);
}

// Round 6
// 159.438 us; speedup vs baseline: 1.0976x; 1.0976x over previous
//
#include <hip/hip_runtime.h>

// out[i,j] = eps[i]*eps_perm[i]*rho/(2*pi*sigma) * exp(-||nuc_i - sb_j||^2/(2*sigma))
//          + eps[i]*d_drop[i]*chi_ambient[j]
// N = 8192 rows (CBs), M = 4096 cols (SBs). f32 in (insertion order), f32 out.
//
// R5 PASSED (dur_us 175, absmax 4.9e-4). rocprof: top-5 dispatches are all
// 512 MiB harness d_ws poisons (81 us each @ 6.5 TB/s); our kernel < 80 us,
// so dur_us is mostly harness re-poison. Kernel floor: 134 MB f32 out
// / 6.3 TB/s ~= 21 us.
//
// R6 changes: 4 rows/block (SB+chi loads register-shared across rows:
// L2 read traffic 393->98 MB) + nontemporal float4 stores (no L2
// write-allocate pollution for the 134 MB stream; fill path shows 6.5 TB/s).

typedef float float4v __attribute__((ext_vector_type(4)));

#define ROWS 4

__global__ __launch_bounds__(256) void rate_kernel(
    const float* __restrict__ nuc,          // [N,2]
    const float* __restrict__ sb,           // [M,2]
    const float* __restrict__ epsilon_perm, // [N]
    const float* __restrict__ epsilon,      // [N]
    const float* __restrict__ d_drop,       // [N]
    const float* __restrict__ rho_SB,       // [1]
    const float* __restrict__ sigma_SB,     // [1]
    const float* __restrict__ chi,          // [M]
    float* __restrict__ out,                // [N,M] f32
    int M)
{
    const int r0  = blockIdx.x * ROWS;
    const int tid = threadIdx.x;

    const float rho = rho_SB[0];
    const float sig = sigma_SB[0];
    // exp(-d2/(2s)) = exp2(d2 * (-1/(2s)) * log2(e))
    const float scale = (-0.5f / sig) * 1.4426950408889634f;
    const float cnorm = 0.15915494309189535f / sig;   // 1/(2*pi*sigma)

    // per-row scalars: block-uniform -> SGPRs
    float nx[ROWS], ny[ROWS], coef[ROWS], lamc[ROWS];
#pragma unroll
    for (int r = 0; r < ROWS; ++r) {
        const float2 nxy = ((const float2*)nuc)[r0 + r];
        nx[r] = nxy.x;
        ny[r] = nxy.y;
        const float e = epsilon[r0 + r];
        coef[r] = e * epsilon_perm[r0 + r] * rho * cnorm;
        lamc[r] = e * d_drop[r0 + r];
    }

    const float4* sb4  = (const float4*)sb;   // 2 (x,y) pairs per float4
    const float4* chi4 = (const float4*)chi;

    for (int j0 = tid * 4; j0 < M; j0 += 256 * 4) {
        const float4 s0 = sb4[j0 / 2];
        const float4 s1 = sb4[j0 / 2 + 1];
        const float4 cv = chi4[j0 / 4];
        const float sx[4] = { s0.x, s0.z, s1.x, s1.z };
        const float sy[4] = { s0.y, s0.w, s1.y, s1.w };
        const float ch[4] = { cv.x, cv.y, cv.z, cv.w };

#pragma unroll
        for (int r = 0; r < ROWS; ++r) {
            float4v res;
#pragma unroll
            for (int k = 0; k < 4; ++k) {
                const float dx = nx[r] - sx[k];
                const float dy = ny[r] - sy[k];
                const float d2 = fmaf(dx, dx, dy * dy);
                const float ev = exp2f(d2 * scale);
                res[k] = fmaf(coef[r], ev, lamc[r] * ch[k]);
            }
            __builtin_nontemporal_store(
                res, (float4v*)(out + (size_t)(r0 + r) * (size_t)M + j0));
        }
    }
}

// tail kernel (1 row/block) — only launched if N % ROWS != 0 (not the case
// for N=8192, kept for robustness)
__global__ __launch_bounds__(256) void rate_kernel_1(
    const float* __restrict__ nuc, const float* __restrict__ sb,
    const float* __restrict__ epsilon_perm, const float* __restrict__ epsilon,
    const float* __restrict__ d_drop, const float* __restrict__ rho_SB,
    const float* __restrict__ sigma_SB, const float* __restrict__ chi,
    float* __restrict__ out, int M, int row0)
{
    const int row = row0 + blockIdx.x;
    const int tid = threadIdx.x;
    const float2 nxy = ((const float2*)nuc)[row];
    const float e   = epsilon[row];
    const float sig = sigma_SB[0];
    const float scale = (-0.5f / sig) * 1.4426950408889634f;
    const float coef = e * epsilon_perm[row] * rho_SB[0] * (0.15915494309189535f / sig);
    const float lamc = e * d_drop[row];
    float* orow = out + (size_t)row * (size_t)M;
    for (int j = tid; j < M; j += 256) {
        const float dx = nxy.x - sb[2 * j];
        const float dy = nxy.y - sb[2 * j + 1];
        const float ev = exp2f(fmaf(dx, dx, dy * dy) * scale);
        orow[j] = fmaf(coef, ev, lamc * chi[j]);
    }
}

extern "C" void kernel_launch(void* const* d_in, const int* in_sizes, int n_in,
                              void* d_out, int out_size, void* d_ws, size_t ws_size,
                              hipStream_t stream) {
    // INSERTION (setup_inputs dict) order.
    const float* nuc = (const float*)d_in[0]; // nuc_locations [N,2]
    const float* sb  = (const float*)d_in[1]; // SB_locations [M,2]
    const float* epp = (const float*)d_in[2]; // epsilon_perm [N]
    const float* eps = (const float*)d_in[3]; // epsilon [N]
    const float* ddp = (const float*)d_in[4]; // d_drop [N]
    const float* rho = (const float*)d_in[5]; // rho_SB [1]
    const float* sig = (const float*)d_in[6]; // sigma_SB [1]
    const float* chi = (const float*)d_in[7]; // chi_ambient [M]
    float* out = (float*)d_out;

    const int M = in_sizes[7];   // 4096 (chi_ambient)
    const int N = out_size / M;  // 8192

    const int nb = N / ROWS;
    if (nb > 0)
        rate_kernel<<<nb, 256, 0, stream>>>(nuc, sb, epp, eps, ddp, rho, sig,
                                            chi, out, M);
    const int tail = N - nb * ROWS;
    if (tail > 0)
        rate_kernel_1<<<tail, 256, 0, stream>>>(nuc, sb, epp, eps, ddp, rho,
                                                sig, chi, out, M, nb * ROWS);
}